// Round 6
// baseline (3952.024 us; speedup 1.0000x reference)
//
#include <hip/hip_runtime.h>
#include <float.h>

#define NLVL 12
#define NB   16
#define TPB  256

// meta: [0..16) cf | [16..32) cb | [32..48) co | [48..64) curf | [64..80) curb |
//       [80..96) curo | [96..109) base_f | [128..141) base_b | [160..177) base_o
// packed entry: id(18b) | fl(4b)<<18 | bl(4b)<<22

struct Params {
    const int *nt, *ninv, *src, *dst, *fl, *bl, *batch;
    const float *We, *be, *Wf, *bf, *Wb, *bb;
    float *h, *hN, *hB, *out;
    int *rowptr, *cursor, *col, *nb_f, *nb_b, *onodes, *bsums, *meta, *plarr, *flag;
    int N, E, M, outN;
};

// ---------------- setup: zero rowptr/meta/flags, init out ----------------
__global__ void k_setup0(Params p) {
    int g = blockIdx.x * blockDim.x + threadIdx.x, gs = gridDim.x * blockDim.x;
    for (int i = g; i < p.M + 1; i += gs) p.rowptr[i] = 0;
    for (int i = g; i < 48; i += gs) p.meta[i] = 0;
    for (int i = g; i < p.N; i += gs) p.flag[i] = 0;
    for (int i = g; i < p.outN; i += gs)
        p.out[i] = ((i & 127) < 64) ? -FLT_MAX : 0.0f;   // max-pool init == finfo.min
}

// ---------------- degrees + histograms + packed levels ----------------
__global__ void k_deg_hist(Params p) {
    __shared__ int hf[NLVL], hb[NLVL], ho[NB];
    if (threadIdx.x < NLVL) { hf[threadIdx.x] = 0; hb[threadIdx.x] = 0; }
    if (threadIdx.x < NB) ho[threadIdx.x] = 0;
    __syncthreads();
    int g = blockIdx.x * blockDim.x + threadIdx.x, gs = gridDim.x * blockDim.x;
    for (int e = g; e < p.E; e += gs) {
        atomicAdd(&p.rowptr[p.dst[e]], 1);
        atomicAdd(&p.rowptr[p.N + p.src[e]], 1);
    }
    for (int i = g; i < p.N; i += gs) {
        int f = p.fl[i], b = p.bl[i];
        p.plarr[i] = f | (b << 4);
        atomicAdd(&hf[f], 1);
        atomicAdd(&hb[b], 1);
        if (p.nt[i] == 1) atomicAdd(&ho[p.batch[i]], 1);
    }
    __syncthreads();
    if (threadIdx.x < NLVL) { atomicAdd(&p.meta[threadIdx.x], hf[threadIdx.x]); atomicAdd(&p.meta[16 + threadIdx.x], hb[threadIdx.x]); }
    if (threadIdx.x < NB) atomicAdd(&p.meta[32 + threadIdx.x], ho[threadIdx.x]);
}

// ---------------- 3-kernel exclusive scan over M = 2N ----------------
__global__ void k_scan1(int* __restrict__ data, int M, int* __restrict__ bsums) {
    __shared__ int s[512];
    int t = threadIdx.x;
    int g = blockIdx.x * 512 + t;
    int v = (g < M) ? data[g] : 0;
    s[t] = v;
    __syncthreads();
    for (int off = 1; off < 512; off <<= 1) {
        int add = (t >= off) ? s[t - off] : 0;
        __syncthreads();
        s[t] += add;
        __syncthreads();
    }
    if (g < M) data[g] = s[t] - v;
    if (t == 511) bsums[blockIdx.x] = s[511];
}

__global__ void k_scan_top(int* __restrict__ bsums, int nblk, int* __restrict__ meta) {
    __shared__ int s[1024];
    int t = threadIdx.x;
    if (t == 0) { int a = 0; for (int l = 0; l < NLVL; l++) { meta[96 + l] = a; meta[48 + l] = a; a += meta[l]; } meta[96 + NLVL] = a; }
    if (t == 1) { int a = 0; for (int l = 0; l < NLVL; l++) { meta[128 + l] = a; meta[64 + l] = a; a += meta[16 + l]; } meta[128 + NLVL] = a; }
    if (t == 2) { int a = 0; for (int b = 0; b < NB; b++) { meta[160 + b] = a; meta[80 + b] = a; a += meta[32 + b]; } meta[160 + NB] = a; }
    int v = (t < nblk) ? bsums[t] : 0;
    s[t] = v;
    __syncthreads();
    for (int off = 1; off < 1024; off <<= 1) {
        int add = (t >= off) ? s[t - off] : 0;
        __syncthreads();
        s[t] += add;
        __syncthreads();
    }
    if (t < nblk) bsums[t] = s[t] - v;
}

__global__ void k_scan_add(int* __restrict__ rowptr, int* __restrict__ cursor, int M, int total,
                           const int* __restrict__ bsums) {
    int g = blockIdx.x * blockDim.x + threadIdx.x;
    if (g >= M) return;
    int r = rowptr[g] + bsums[g >> 9];
    rowptr[g] = r;
    cursor[g] = r;
    if (g == 0) rowptr[M] = total;
}

// ---------------- fused: packed CSR fill + packed node scatter + encoder ----------------
__global__ void k_fill(Params p) {
    __shared__ int hf[NLVL], hb[NLVL], ho[NB], basef[NLVL], baseb[NLVL], baseo[NB];
    int g = blockIdx.x * blockDim.x + threadIdx.x, gs = gridDim.x * blockDim.x;
    int tid = threadIdx.x;
    int N = p.N;

    for (int e = g; e < p.E; e += gs) {
        int s = p.src[e], d = p.dst[e];
        p.col[atomicAdd(&p.cursor[d], 1)] = s | (p.plarr[s] << 18);      // in-edge: other = src
        p.col[atomicAdd(&p.cursor[N + s], 1)] = d | (p.plarr[d] << 18);  // out-edge: other = dst
    }

    for (int i0 = blockIdx.x * TPB; i0 < N; i0 += gs) {
        int i = i0 + tid;
        bool valid = (i < N);
        if (tid < NLVL) { hf[tid] = 0; hb[tid] = 0; }
        if (tid < NB) ho[tid] = 0;
        __syncthreads();
        int lf = 0, lb = 0, ob = -1;
        if (valid) {
            lf = p.fl[i]; lb = p.bl[i];
            atomicAdd(&hf[lf], 1);
            atomicAdd(&hb[lb], 1);
            if (p.nt[i] == 1) { ob = p.batch[i]; atomicAdd(&ho[ob], 1); }
        }
        __syncthreads();
        if (tid < NLVL) {
            basef[tid] = atomicAdd(&p.meta[48 + tid], hf[tid]);
            baseb[tid] = atomicAdd(&p.meta[64 + tid], hb[tid]);
            hf[tid] = 0; hb[tid] = 0;
        }
        if (tid < NB) {
            baseo[tid] = atomicAdd(&p.meta[80 + tid], ho[tid]);
            ho[tid] = 0;
        }
        __syncthreads();
        if (valid) {
            int pk = i | ((lf | (lb << 4)) << 18);
            p.nb_f[basef[lf] + atomicAdd(&hf[lf], 1)] = pk;
            p.nb_b[baseb[lb] + atomicAdd(&hb[lb], 1)] = pk;
            if (ob >= 0) p.onodes[baseo[ob] + atomicAdd(&ho[ob], 1)] = pk;
        }
        __syncthreads();
    }

    for (int t = g; t < N * 16; t += gs) {
        int v = t >> 4;
        int j = (t & 15) * 4;
        float a = (float)p.nt[v], c = (float)p.ninv[v];
        float4 w0 = *(const float4*)(p.We + j);
        float4 w1 = *(const float4*)(p.We + 64 + j);
        float4 b  = *(const float4*)(p.be + j);
        float4 r;
        r.x = fmaf(a, w0.x, fmaf(c, w1.x, b.x));
        r.y = fmaf(a, w0.y, fmaf(c, w1.y, b.y));
        r.z = fmaf(a, w0.z, fmaf(c, w1.z, b.z));
        r.w = fmaf(a, w0.w, fmaf(c, w1.w, b.w));
        *(float4*)(p.h + (size_t)v * 64 + j) = r;
    }
}

// ---------------- dataflow sweep + readout (single cooperative dispatch, NO barriers) ----------------
#define LDA(ptr) __int_as_float(__hip_atomic_load((const int*)(ptr), __ATOMIC_RELAXED, __HIP_MEMORY_SCOPE_AGENT))

__device__ __forceinline__ void spin_flag(const int* f, int bit) {
    int gd = 0;
    while (!(__hip_atomic_load(f, __ATOMIC_RELAXED, __HIP_MEMORY_SCOPE_AGENT) & bit)
           && ++gd < (1 << 23))
        __builtin_amdgcn_s_sleep(2);
}

__device__ inline void atomicMaxF(float* addr, float val) {
    int* ai = (int*)addr;
    int old = __hip_atomic_load(ai, __ATOMIC_RELAXED, __HIP_MEMORY_SCOPE_AGENT);
    while (__int_as_float(old) < val) {
        int assumed = old;
        old = atomicCAS(ai, assumed, __float_as_int(val));
        if (old == assumed) break;
    }
}

__global__ __launch_bounds__(TPB, 4) void k_flow(Params p) {
    __shared__ float Ws[2 * 4096];
    const int tid = threadIdx.x, lane = tid & 63;
    for (int i = tid; i < 4096; i += TPB) { Ws[i] = p.Wf[i]; Ws[4096 + i] = p.Wb[i]; }
    __syncthreads();

    const int N = p.N;
    const int base1f = p.meta[97];            // base_f[1]
    const int base1b = p.meta[129];           // base_b[1]
    const int T1 = N - base1f, T2 = N - base1b, T = T1 + T2;
    const int wid = (blockIdx.x * TPB + tid) >> 6;
    const int nw  = (gridDim.x * TPB) >> 6;
    const int q = lane >> 4, fb = (lane & 15) * 4;
    const float bvf = p.bf[lane], bvb = p.bb[lane];

    int c0 = (int)((long long)T * wid / nw);
    int c1 = (int)((long long)T * (wid + 1) / nw);

    for (int g0 = c0; g0 < c1; g0 += 64) {
        int take = c1 - g0; if (take > 64) take = 64;
        int el = 0, rpvl = 0, rpel = 0, dirl = 0;
        if (lane < take) {
            int t = g0 + lane;
            int d_ = (t >= T1) ? 1 : 0;
            int e = d_ ? p.nb_b[base1b + (t - T1)] : p.nb_f[base1f + t];
            const int* rp_ = d_ ? (p.rowptr + N) : p.rowptr;
            int v = e & 0x3FFFF;
            el = e; dirl = d_;
            rpvl = rp_[v]; rpel = rp_[v + 1];
        }
        for (int j = 0; j < take; j++) {
            int e   = __shfl(el, j, 64);
            int d_  = __shfl(dirl, j, 64);
            int rpv = __shfl(rpvl, j, 64);
            int rpe = __shfl(rpel, j, 64);
            int v   = e & 0x3FFFF;
            int lvl = d_ ? ((e >> 22) & 15) : ((e >> 18) & 15);

            float4 acc = make_float4(0.f, 0.f, 0.f, 0.f);
            for (int cb = rpv + q; cb < rpe; cb += 4) {
                int cu = p.col[cb];
                int u = cu & 0x3FFFF;
                int flu = (cu >> 18) & 15, blu = (cu >> 22) & 15;
                const float* sb; int bit;
                if (!d_) {
                    if (flu > 0 && flu < lvl) { sb = p.hN; bit = 1; }
                    else                      { sb = p.h;  bit = 0; }
                } else {
                    if (blu > 0 && blu < lvl) { sb = p.hB; bit = 2; }
                    else if (flu > 0)         { sb = p.hN; bit = 1; }
                    else                      { sb = p.h;  bit = 0; }
                }
                if (bit) spin_flag(&p.flag[u], bit);
                const float* bp = sb + (size_t)u * 64 + fb;
                acc.x += LDA(bp + 0);
                acc.y += LDA(bp + 1);
                acc.z += LDA(bp + 2);
                acc.w += LDA(bp + 3);
            }
            acc.x += __shfl_xor(acc.x, 16, 64); acc.y += __shfl_xor(acc.y, 16, 64);
            acc.z += __shfl_xor(acc.z, 16, 64); acc.w += __shfl_xor(acc.w, 16, 64);
            acc.x += __shfl_xor(acc.x, 32, 64); acc.y += __shfl_xor(acc.y, 32, 64);
            acc.z += __shfl_xor(acc.z, 32, 64); acc.w += __shfl_xor(acc.w, 32, 64);

            float o = (d_ ? bvb : bvf) * (float)(rpe - rpv);
            const float* W = Ws + (d_ ? 4096 : 0);
            #pragma unroll
            for (int k = 0; k < 16; k++) {
                float ax = __shfl(acc.x, k, 64);
                float ay = __shfl(acc.y, k, 64);
                float az = __shfl(acc.z, k, 64);
                float aw = __shfl(acc.w, k, 64);
                o = fmaf(ax, W[(4 * k + 0) * 64 + lane], o);
                o = fmaf(ay, W[(4 * k + 1) * 64 + lane], o);
                o = fmaf(az, W[(4 * k + 2) * 64 + lane], o);
                o = fmaf(aw, W[(4 * k + 3) * 64 + lane], o);
            }
            float* db = d_ ? p.hB : p.hN;
            __hip_atomic_store((int*)(db + (size_t)v * 64 + lane), __float_as_int(o),
                               __ATOMIC_RELAXED, __HIP_MEMORY_SCOPE_AGENT);
            asm volatile("s_waitcnt vmcnt(0)" ::: "memory");   // data committed at coherence point
            if (lane == 0)
                __hip_atomic_fetch_or(&p.flag[v], d_ ? 2 : 1,
                                      __ATOMIC_RELAXED, __HIP_MEMORY_SCOPE_AGENT);
        }
    }

    // ---------- readout: spin on final flags, no barrier ----------
    {
        const int S = nw / NB;
        int b = wid / S, sl = wid % S;
        if (b < NB) {
            int a0 = p.meta[160 + b], a1 = p.meta[161 + b];
            int cnt = a1 - a0;
            if (cnt > 0) {
                int lo = a0 + (int)(((long long)cnt * sl) / S);
                int hi = a0 + (int)(((long long)cnt * (sl + 1)) / S);
                if (hi > lo) {
                    float mx = -FLT_MAX, sm = 0.f;
                    for (int k = lo; k < hi; k += 64) {
                        int take = hi - k; if (take > 64) take = 64;
                        int elr = (lane < take) ? p.onodes[k + lane] : 0;
                        for (int j = 0; j < take; j++) {
                            int e = __shfl(elr, j, 64);
                            int v = e & 0x3FFFF;
                            int flv = (e >> 18) & 15, blv = (e >> 22) & 15;
                            const float* sb; int bit;
                            if (blv > 0)      { sb = p.hB; bit = 2; }
                            else if (flv > 0) { sb = p.hN; bit = 1; }
                            else              { sb = p.h;  bit = 0; }
                            if (bit) spin_flag(&p.flag[v], bit);
                            float x = LDA(sb + (size_t)v * 64 + lane);
                            mx = fmaxf(mx, x);
                            sm += x;
                        }
                    }
                    atomicMaxF(&p.out[b * 128 + lane], mx);
                    atomicAdd(&p.out[b * 128 + 64 + lane], sm);
                }
            }
        }
    }
}

extern "C" void kernel_launch(void* const* d_in, const int* in_sizes, int n_in,
                              void* d_out, int out_size, void* d_ws, size_t ws_size,
                              hipStream_t stream) {
    int N = in_sizes[0];
    int E = in_sizes[2] / 2;
    int M = 2 * N;

    Params p;
    p.nt    = (const int*)d_in[0];
    p.ninv  = (const int*)d_in[1];
    p.src   = (const int*)d_in[2];
    p.dst   = (const int*)d_in[2] + E;
    p.fl    = (const int*)d_in[3];
    p.bl    = (const int*)d_in[4];
    p.batch = (const int*)d_in[5];
    p.We    = (const float*)d_in[6];
    p.be    = (const float*)d_in[7];
    p.Wf    = (const float*)d_in[8];
    p.bf    = (const float*)d_in[9];
    p.Wb    = (const float*)d_in[10];
    p.bb    = (const float*)d_in[11];
    p.out   = (float*)d_out;
    p.N = N; p.E = E; p.M = M; p.outN = out_size;

    char* ws = (char*)d_ws;
    size_t off = 0;
    auto alloc = [&](size_t bytes) -> char* {
        char* q = ws + off;
        off = (off + bytes + 255) & ~(size_t)255;
        return q;
    };
    p.h      = (float*)alloc((size_t)N * 64 * sizeof(float));
    p.hN     = (float*)alloc((size_t)N * 64 * sizeof(float));
    p.hB     = (float*)alloc((size_t)N * 64 * sizeof(float));
    p.rowptr = (int*)  alloc((size_t)(M + 1) * sizeof(int));
    p.cursor = (int*)  alloc((size_t)M * sizeof(int));
    p.col    = (int*)  alloc((size_t)2 * E * sizeof(int));
    p.nb_f   = (int*)  alloc((size_t)N * sizeof(int));
    p.nb_b   = (int*)  alloc((size_t)N * sizeof(int));
    p.onodes = (int*)  alloc((size_t)N * sizeof(int));
    p.plarr  = (int*)  alloc((size_t)N * sizeof(int));
    p.flag   = (int*)  alloc((size_t)N * sizeof(int));
    p.bsums  = (int*)  alloc(1024 * sizeof(int));
    p.meta   = (int*)  alloc(256 * sizeof(int));

    int nscan = (M + 511) / 512;            // 782 <= 1024

    k_setup0<<<512, 256, 0, stream>>>(p);
    k_deg_hist<<<512, 256, 0, stream>>>(p);
    k_scan1<<<nscan, 512, 0, stream>>>(p.rowptr, M, p.bsums);
    k_scan_top<<<1, 1024, 0, stream>>>(p.bsums, nscan, p.meta);
    k_scan_add<<<(M + 255) / 256, 256, 0, stream>>>(p.rowptr, p.cursor, M, 2 * E, p.bsums);
    k_fill<<<1024, 256, 0, stream>>>(p);

    // cooperative co-residency for the dataflow kernel (spin-waits require it)
    int occ = 0;
    hipOccupancyMaxActiveBlocksPerMultiprocessor(&occ, k_flow, TPB, 0);
    if (occ < 1) occ = 1;
    int G = occ * 256;
    if (G > 2048) G = 2048;

    void* args[] = { &p };
    hipLaunchCooperativeKernel((void*)k_flow, dim3(G), dim3(TPB), args, 0, stream);
}

// Round 7
// 693.373 us; speedup vs baseline: 5.6997x; 5.6997x over previous
//
#include <hip/hip_runtime.h>
#include <float.h>

#define NLVL 12
#define NB   16

// meta: [0..16) cf | [16..32) cb | [32..48) co | [48..64) curf | [64..80) curb |
//       [80..96) curo | [96..109) base_f | [128..141) base_b | [160..177) base_o
// packed entry: id(18b) | fl(4b)<<18 | bl(4b)<<22   (N=200k < 2^18)

struct Params {
    const int *nt, *ninv, *src, *dst, *fl, *bl, *batch;
    const float *We, *be, *Wf, *bf, *Wb, *bb;
    float *h, *hN, *out;
    int *rowptr, *cursor, *col, *nb_f, *nb_b, *onodes, *bsums, *meta, *plarr;
    int N, E, M, outN;
};

// ---------------- degrees + histograms + packed levels ----------------
__global__ void k_deg_hist(Params p) {
    __shared__ int hf[NLVL], hb[NLVL], ho[NB];
    if (threadIdx.x < NLVL) { hf[threadIdx.x] = 0; hb[threadIdx.x] = 0; }
    if (threadIdx.x < NB) ho[threadIdx.x] = 0;
    __syncthreads();
    int g = blockIdx.x * blockDim.x + threadIdx.x, gs = gridDim.x * blockDim.x;
    for (int e = g; e < p.E; e += gs) {
        atomicAdd(&p.rowptr[p.dst[e]], 1);
        atomicAdd(&p.rowptr[p.N + p.src[e]], 1);
    }
    for (int i = g; i < p.N; i += gs) {
        int f = p.fl[i], b = p.bl[i];
        p.plarr[i] = f | (b << 4);
        atomicAdd(&hf[f], 1);
        atomicAdd(&hb[b], 1);
        if (p.nt[i] == 1) atomicAdd(&ho[p.batch[i]], 1);
    }
    __syncthreads();
    if (threadIdx.x < NLVL) { atomicAdd(&p.meta[threadIdx.x], hf[threadIdx.x]); atomicAdd(&p.meta[16 + threadIdx.x], hb[threadIdx.x]); }
    if (threadIdx.x < NB) atomicAdd(&p.meta[32 + threadIdx.x], ho[threadIdx.x]);
}

// ---------------- 3-kernel exclusive scan over M = 2N ----------------
__global__ void k_scan1(int* __restrict__ data, int M, int* __restrict__ bsums) {
    __shared__ int s[512];
    int t = threadIdx.x;
    int g = blockIdx.x * 512 + t;
    int v = (g < M) ? data[g] : 0;
    s[t] = v;
    __syncthreads();
    for (int off = 1; off < 512; off <<= 1) {
        int add = (t >= off) ? s[t - off] : 0;
        __syncthreads();
        s[t] += add;
        __syncthreads();
    }
    if (g < M) data[g] = s[t] - v;
    if (t == 511) bsums[blockIdx.x] = s[511];
}

__global__ void k_scan_top(int* __restrict__ bsums, int nblk, int* __restrict__ meta,
                           float* __restrict__ out, int outN) {
    __shared__ int s[1024];
    int t = threadIdx.x;
    if (t == 0) { int a = 0; for (int l = 0; l < NLVL; l++) { meta[96 + l] = a; meta[48 + l] = a; a += meta[l]; } meta[96 + NLVL] = a; }
    if (t == 1) { int a = 0; for (int l = 0; l < NLVL; l++) { meta[128 + l] = a; meta[64 + l] = a; a += meta[16 + l]; } meta[128 + NLVL] = a; }
    if (t == 2) { int a = 0; for (int b = 0; b < NB; b++) { meta[160 + b] = a; meta[80 + b] = a; a += meta[32 + b]; } meta[160 + NB] = a; }
    // out init: [B][128], cols 0..63 max-pool -> -FLT_MAX (finfo.min), 64..127 sum-pool -> 0
    for (int i = t; i < outN; i += 1024)
        out[i] = ((i & 127) < 64) ? -FLT_MAX : 0.0f;
    int v = (t < nblk) ? bsums[t] : 0;
    s[t] = v;
    __syncthreads();
    for (int off = 1; off < 1024; off <<= 1) {
        int add = (t >= off) ? s[t - off] : 0;
        __syncthreads();
        s[t] += add;
        __syncthreads();
    }
    if (t < nblk) bsums[t] = s[t] - v;
}

__global__ void k_scan_add(int* __restrict__ rowptr, int* __restrict__ cursor, int M, int total,
                           const int* __restrict__ bsums) {
    int g = blockIdx.x * blockDim.x + threadIdx.x;
    if (g >= M) return;
    int r = rowptr[g] + bsums[g >> 9];
    rowptr[g] = r;
    cursor[g] = r;
    if (g == 0) rowptr[M] = total;
}

// ---------------- fused: packed CSR fill + packed node scatter + encoder ----------------
__global__ void k_fill(Params p) {
    __shared__ int hf[NLVL], hb[NLVL], ho[NB], basef[NLVL], baseb[NLVL], baseo[NB];
    int g = blockIdx.x * blockDim.x + threadIdx.x, gs = gridDim.x * blockDim.x;
    int tid = threadIdx.x;
    int N = p.N;

    for (int e = g; e < p.E; e += gs) {
        int s = p.src[e], d = p.dst[e];
        p.col[atomicAdd(&p.cursor[d], 1)] = s | (p.plarr[s] << 18);      // in-edge: other = src
        p.col[atomicAdd(&p.cursor[N + s], 1)] = d | (p.plarr[d] << 18);  // out-edge: other = dst
    }

    for (int i0 = blockIdx.x * blockDim.x; i0 < N; i0 += gs) {
        int i = i0 + tid;
        bool valid = (i < N);
        if (tid < NLVL) { hf[tid] = 0; hb[tid] = 0; }
        if (tid < NB) ho[tid] = 0;
        __syncthreads();
        int lf = 0, lb = 0, ob = -1;
        if (valid) {
            lf = p.fl[i]; lb = p.bl[i];
            atomicAdd(&hf[lf], 1);
            atomicAdd(&hb[lb], 1);
            if (p.nt[i] == 1) { ob = p.batch[i]; atomicAdd(&ho[ob], 1); }
        }
        __syncthreads();
        if (tid < NLVL) {
            basef[tid] = atomicAdd(&p.meta[48 + tid], hf[tid]);
            baseb[tid] = atomicAdd(&p.meta[64 + tid], hb[tid]);
            hf[tid] = 0; hb[tid] = 0;
        }
        if (tid < NB) {
            baseo[tid] = atomicAdd(&p.meta[80 + tid], ho[tid]);
            ho[tid] = 0;
        }
        __syncthreads();
        if (valid) {
            int pk = i | ((lf | (lb << 4)) << 18);
            p.nb_f[basef[lf] + atomicAdd(&hf[lf], 1)] = pk;
            p.nb_b[baseb[lb] + atomicAdd(&hb[lb], 1)] = pk;
            if (ob >= 0) p.onodes[baseo[ob] + atomicAdd(&ho[ob], 1)] = pk;
        }
        __syncthreads();
    }

    for (int t = g; t < N * 16; t += gs) {
        int v = t >> 4;
        int j = (t & 15) * 4;
        float a = (float)p.nt[v], c = (float)p.ninv[v];
        float4 w0 = *(const float4*)(p.We + j);
        float4 w1 = *(const float4*)(p.We + 64 + j);
        float4 b  = *(const float4*)(p.be + j);
        float4 r;
        r.x = fmaf(a, w0.x, fmaf(c, w1.x, b.x));
        r.y = fmaf(a, w0.y, fmaf(c, w1.y, b.y));
        r.z = fmaf(a, w0.z, fmaf(c, w1.z, b.z));
        r.w = fmaf(a, w0.w, fmaf(c, w1.w, b.w));
        *(float4*)(p.h + (size_t)v * 64 + j) = r;
    }
}

// ---------------- fused per-level sweep: gather + matvec (packed levels, no extra loads) ----
// Parity (verified r4/r5): fwd reads hN iff 0<flu<l, writes hN always;
//                          bwd reads hN iff (flu>0) != (0<blu<l), writes (flu>0? h : hN).
__global__ __launch_bounds__(256) void k_sweep(Params p, int lvl, int dir) {
    __shared__ float Ws[4096];
    const float* W = dir ? p.Wb : p.Wf;
    for (int i = threadIdx.x; i < 4096; i += 256) Ws[i] = W[i];
    __syncthreads();
    const int* nb = dir ? p.nb_b : p.nb_f;
    const int* rp = p.rowptr + (dir ? p.N : 0);
    int start = p.meta[(dir ? 128 : 96) + lvl];
    int cnt   = p.meta[(dir ? 128 : 96) + lvl + 1] - start;
    const int lane = threadIdx.x & 63;
    const int wid  = (blockIdx.x * blockDim.x + threadIdx.x) >> 6;
    const int nw   = (gridDim.x * blockDim.x) >> 6;
    const int q = lane >> 4, fb = (lane & 15) * 4;
    float bv = (dir ? p.bb : p.bf)[lane];

    int c0 = (int)((long long)cnt * wid / nw);
    int c1 = (int)((long long)cnt * (wid + 1) / nw);
    for (int g0 = c0; g0 < c1; g0 += 64) {
        int take = c1 - g0; if (take > 64) take = 64;
        int el = 0, rpvl = 0, rpel = 0;
        if (lane < take) {
            int e = nb[start + g0 + lane];      // coalesced id preload
            el = e;
            int v = e & 0x3FFFF;
            rpvl = rp[v]; rpel = rp[v + 1];     // pipelined pointer loads
        }
        for (int j = 0; j < take; j++) {
            int e   = __shfl(el, j, 64);
            int rpv = __shfl(rpvl, j, 64);
            int rpe = __shfl(rpel, j, 64);
            int v   = e & 0x3FFFF;
            int flv = (e >> 18) & 15;
            float4 acc = make_float4(0.f, 0.f, 0.f, 0.f);
            for (int cb = rpv + q; cb < rpe; cb += 4) {
                int cu = p.col[cb];             // broadcast within quarter-wave
                int u = cu & 0x3FFFF;
                int flu = (cu >> 18) & 15, blu = (cu >> 22) & 15;
                bool useN = (dir == 0) ? (flu > 0 && flu < lvl)
                                       : ((flu > 0) != (blu > 0 && blu < lvl));
                const float* sb = useN ? p.hN : p.h;
                const float4 x = *(const float4*)(sb + (size_t)u * 64 + fb);
                acc.x += x.x; acc.y += x.y; acc.z += x.z; acc.w += x.w;
            }
            acc.x += __shfl_xor(acc.x, 16, 64); acc.y += __shfl_xor(acc.y, 16, 64);
            acc.z += __shfl_xor(acc.z, 16, 64); acc.w += __shfl_xor(acc.w, 16, 64);
            acc.x += __shfl_xor(acc.x, 32, 64); acc.y += __shfl_xor(acc.y, 32, 64);
            acc.z += __shfl_xor(acc.z, 32, 64); acc.w += __shfl_xor(acc.w, 32, 64);
            float o = bv * (float)(rpe - rpv);
            #pragma unroll
            for (int k = 0; k < 16; k++) {
                float ax = __shfl(acc.x, k, 64);
                float ay = __shfl(acc.y, k, 64);
                float az = __shfl(acc.z, k, 64);
                float aw = __shfl(acc.w, k, 64);
                o = fmaf(ax, Ws[(4 * k + 0) * 64 + lane], o);
                o = fmaf(ay, Ws[(4 * k + 1) * 64 + lane], o);
                o = fmaf(az, Ws[(4 * k + 2) * 64 + lane], o);
                o = fmaf(aw, Ws[(4 * k + 3) * 64 + lane], o);
            }
            float* db = (dir == 0) ? p.hN : ((flv > 0) ? p.h : p.hN);
            db[(size_t)v * 64 + lane] = o;
        }
    }
}

// ---------------- readout (packed onodes) ----------------
__device__ inline void atomicMaxF(float* addr, float val) {
    int* ai = (int*)addr;
    int old = *ai;
    while (__int_as_float(old) < val) {
        int assumed = old;
        old = atomicCAS(ai, assumed, __float_as_int(val));
        if (old == assumed) break;
    }
}

__global__ void k_readout(Params p) {
    int b = blockIdx.x >> 5;          // batch
    int sl = blockIdx.x & 31;         // slice
    int a0 = p.meta[160 + b], a1 = p.meta[161 + b];
    int cnt = a1 - a0;
    if (cnt == 0) return;
    int lo = a0 + (int)((long long)cnt * sl / 32);
    int hi = a0 + (int)((long long)cnt * (sl + 1) / 32);
    int wcnt = hi - lo;
    int wave = threadIdx.x >> 6, lane = threadIdx.x & 63;
    int wl = lo + (wcnt * wave) / 4;
    int wh = lo + (wcnt * (wave + 1)) / 4;
    if (wh <= wl) return;
    float mx = -FLT_MAX, sm = 0.f;
    for (int k = wl; k < wh; k += 64) {
        int take = wh - k; if (take > 64) take = 64;
        int el = (lane < take) ? p.onodes[k + lane] : 0;
        for (int j = 0; j < take; j++) {
            int e = __shfl(el, j, 64);
            int v = e & 0x3FFFF;
            int flv = (e >> 18) & 15, blv = (e >> 22) & 15;
            const float* sb = ((flv > 0) != (blv > 0)) ? p.hN : p.h;  // final buffer
            float x = sb[(size_t)v * 64 + lane];
            mx = fmaxf(mx, x);
            sm += x;
        }
    }
    atomicMaxF(&p.out[b * 128 + lane], mx);
    atomicAdd(&p.out[b * 128 + 64 + lane], sm);
}

extern "C" void kernel_launch(void* const* d_in, const int* in_sizes, int n_in,
                              void* d_out, int out_size, void* d_ws, size_t ws_size,
                              hipStream_t stream) {
    int N = in_sizes[0];
    int E = in_sizes[2] / 2;
    int M = 2 * N;

    Params p;
    p.nt    = (const int*)d_in[0];
    p.ninv  = (const int*)d_in[1];
    p.src   = (const int*)d_in[2];
    p.dst   = (const int*)d_in[2] + E;
    p.fl    = (const int*)d_in[3];
    p.bl    = (const int*)d_in[4];
    p.batch = (const int*)d_in[5];
    p.We    = (const float*)d_in[6];
    p.be    = (const float*)d_in[7];
    p.Wf    = (const float*)d_in[8];
    p.bf    = (const float*)d_in[9];
    p.Wb    = (const float*)d_in[10];
    p.bb    = (const float*)d_in[11];
    p.out   = (float*)d_out;
    p.N = N; p.E = E; p.M = M; p.outN = out_size;

    char* ws = (char*)d_ws;
    size_t off = 0;
    auto alloc = [&](size_t bytes) -> char* {
        char* q = ws + off;
        off = (off + bytes + 255) & ~(size_t)255;
        return q;
    };
    // rowptr + meta adjacent -> one memset zeroes both
    p.rowptr = (int*)  alloc((size_t)(M + 1) * sizeof(int));
    p.meta   = (int*)  alloc(256 * sizeof(int));
    size_t zbytes = (size_t)((char*)(p.meta + 256) - (char*)p.rowptr);
    p.h      = (float*)alloc((size_t)N * 64 * sizeof(float));
    p.hN     = (float*)alloc((size_t)N * 64 * sizeof(float));
    p.cursor = (int*)  alloc((size_t)M * sizeof(int));
    p.col    = (int*)  alloc((size_t)2 * E * sizeof(int));
    p.nb_f   = (int*)  alloc((size_t)N * sizeof(int));
    p.nb_b   = (int*)  alloc((size_t)N * sizeof(int));
    p.onodes = (int*)  alloc((size_t)N * sizeof(int));
    p.plarr  = (int*)  alloc((size_t)N * sizeof(int));
    p.bsums  = (int*)  alloc(1024 * sizeof(int));

    int nscan = (M + 511) / 512;            // 782 <= 1024

    hipMemsetAsync(p.rowptr, 0, zbytes, stream);
    k_deg_hist<<<512, 256, 0, stream>>>(p);
    k_scan1<<<nscan, 512, 0, stream>>>(p.rowptr, M, p.bsums);
    k_scan_top<<<1, 1024, 0, stream>>>(p.bsums, nscan, p.meta, p.out, out_size);
    k_scan_add<<<(M + 255) / 256, 256, 0, stream>>>(p.rowptr, p.cursor, M, 2 * E, p.bsums);
    k_fill<<<1024, 256, 0, stream>>>(p);

    for (int l = 1; l < NLVL; l++)
        k_sweep<<<512, 256, 0, stream>>>(p, l, 0);
    for (int l = 1; l < NLVL; l++)
        k_sweep<<<512, 256, 0, stream>>>(p, l, 1);

    k_readout<<<NB * 32, 256, 0, stream>>>(p);
}